// Round 1
// baseline (4117.158 us; speedup 1.0000x reference)
//
#include <hip/hip_runtime.h>

// Problem constants
#define M_TOK 32000   // B*T = 16*2000 tokens
#define DIM   512     // feature dim
#define KCB   1024    // codebook size
#define NQ    8       // quantizer stages
// GEMM tiling
#define BM 128
#define BN 128
#define BKC 16

__device__ __forceinline__ float wave_reduce_sum(float v) {
#pragma unroll
  for (int off = 32; off > 0; off >>= 1) v += __shfl_xor(v, off, 64);
  return v;
}

// Precompute per-stage codebook norms e2[8*1024], per-token ||x||^2 r2[32000],
// and zero the loss accumulator. One wave per row.
__global__ __launch_bounds__(256) void rvq_init_kernel(
    const float* __restrict__ x, const float* __restrict__ cb,
    float* __restrict__ e2, float* __restrict__ r2, float* __restrict__ lossCell) {
  if (blockIdx.x == 0 && threadIdx.x == 0) *lossCell = 0.f;
  int row = blockIdx.x * 4 + (threadIdx.x >> 6);
  int lane = threadIdx.x & 63;
  const float* src;
  float* dst;
  if (row < NQ * KCB) {
    src = cb + (size_t)row * DIM;
    dst = e2 + row;
  } else {
    int t = row - NQ * KCB;
    if (t >= M_TOK) return;
    src = x + (size_t)t * DIM;
    dst = r2 + t;
  }
  const float4* s4 = (const float4*)src;
  float s = 0.f;
  float4 v = s4[lane];
  s += v.x * v.x + v.y * v.y + v.z * v.z + v.w * v.w;
  v = s4[lane + 64];
  s += v.x * v.x + v.y * v.y + v.z * v.z + v.w * v.w;
  s = wave_reduce_sum(s);
  if (lane == 0) *dst = s;
}

// One VQ stage: fused GEMM (dots) + argmin over all 1024 codewords + gather +
// straight-through residual update + loss partial + next-stage ||r||^2.
// rin may equal rout (in-place residual update; each block owns its rows).
__global__ __launch_bounds__(256) void rvq_stage_kernel(
    const float* __restrict__ rin,   // [32000][512] current residual
    const float* __restrict__ cb,    // [1024][512] this stage's codebook
    const float* __restrict__ e2,    // [1024]
    const float* __restrict__ r2in,  // [32000]
    float* __restrict__ rout,        // [32000][512] next residual
    float* __restrict__ r2out,       // [32000]
    float* __restrict__ idx_out,     // [32000] winning index as float
    float* __restrict__ lossCell) {
  __shared__ float As[BKC][132];   // +4 pad: b128-aligned rows, <=2-way store conflicts
  __shared__ float Bs[BKC][132];
  __shared__ float e2s[KCB];
  __shared__ float rv[BM][17];
  __shared__ int   ri[BM][17];
  __shared__ int   idxs[BM];

  const int tid = threadIdx.x;
  const int tx = tid & 15, ty = tid >> 4;
  const int m0 = blockIdx.x * BM;

  for (int i = tid; i < KCB; i += 256) e2s[i] = e2[i];

  float r2reg[8];
#pragma unroll
  for (int i = 0; i < 8; ++i) r2reg[i] = r2in[m0 + ty * 8 + i];

  float minv[8];
  int mini[8];
#pragma unroll
  for (int i = 0; i < 8; ++i) { minv[i] = 3.4e38f; mini[i] = 0; }

  for (int nc = 0; nc < KCB / BN; ++nc) {
    float acc[8][8];
#pragma unroll
    for (int i = 0; i < 8; ++i)
#pragma unroll
      for (int j = 0; j < 8; ++j) acc[i][j] = 0.f;

    for (int kc = 0; kc < DIM; kc += BKC) {
      __syncthreads();  // protect LDS from previous iteration's readers
#pragma unroll
      for (int t = 0; t < 2; ++t) {
        int f4 = tid + t * 256;          // 512 float4 slots per tile
        int r = f4 >> 2, kg = f4 & 3;    // token/col, k-group of 4
        float4 a = *(const float4*)(rin + (size_t)(m0 + r) * DIM + kc + kg * 4);
        As[kg * 4 + 0][r] = a.x; As[kg * 4 + 1][r] = a.y;
        As[kg * 4 + 2][r] = a.z; As[kg * 4 + 3][r] = a.w;
        float4 b = *(const float4*)(cb + (size_t)(nc * BN + r) * DIM + kc + kg * 4);
        Bs[kg * 4 + 0][r] = b.x; Bs[kg * 4 + 1][r] = b.y;
        Bs[kg * 4 + 2][r] = b.z; Bs[kg * 4 + 3][r] = b.w;
      }
      __syncthreads();
#pragma unroll
      for (int kd = 0; kd < BKC; ++kd) {
        float4 a0 = *(const float4*)&As[kd][ty * 8];
        float4 a1 = *(const float4*)&As[kd][ty * 8 + 4];
        float4 b0 = *(const float4*)&Bs[kd][tx * 8];
        float4 b1 = *(const float4*)&Bs[kd][tx * 8 + 4];
        float av[8] = {a0.x, a0.y, a0.z, a0.w, a1.x, a1.y, a1.z, a1.w};
        float bv[8] = {b0.x, b0.y, b0.z, b0.w, b1.x, b1.y, b1.z, b1.w};
#pragma unroll
        for (int i = 0; i < 8; ++i)
#pragma unroll
          for (int j = 0; j < 8; ++j) acc[i][j] = fmaf(av[i], bv[j], acc[i][j]);
      }
    }
    // fold this N-chunk into the running argmin (reference: (r2 - 2*dot) + e2)
#pragma unroll
    for (int i = 0; i < 8; ++i) {
#pragma unroll
      for (int j = 0; j < 8; ++j) {
        int col = nc * BN + tx * 8 + j;
        float d = (r2reg[i] - 2.f * acc[i][j]) + e2s[col];
        if (d < minv[i]) { minv[i] = d; mini[i] = col; }
      }
    }
  }

  __syncthreads();
#pragma unroll
  for (int i = 0; i < 8; ++i) { rv[ty * 8 + i][tx] = minv[i]; ri[ty * 8 + i][tx] = mini[i]; }
  __syncthreads();
  if (tid < BM) {
    float best = rv[tid][0];
    int bi = ri[tid][0];
#pragma unroll
    for (int t = 1; t < 16; ++t) {
      float v = rv[tid][t];
      int ii = ri[tid][t];
      if (v < best || (v == best && ii < bi)) { best = v; bi = ii; }  // first-index ties
    }
    idxs[tid] = bi;
    idx_out[m0 + tid] = (float)bi;
  }
  __syncthreads();

  // Epilogue: one wave per token row. Replicate reference rounding exactly:
  //   t = q - r; qst = r + t; r_new = r - qst; loss += t^2
  const int wave = tid >> 6, lane = tid & 63;
  float lpart = 0.f;
  for (int r = wave; r < BM; r += 4) {
    const int tok = m0 + r;
    const float4* rrow = (const float4*)(rin + (size_t)tok * DIM);
    const float4* crow = (const float4*)(cb + (size_t)idxs[r] * DIM);
    float4* orow = (float4*)(rout + (size_t)tok * DIM);
    float ssq_t = 0.f, ssq_r = 0.f;
#pragma unroll
    for (int c4 = 0; c4 < 2; ++c4) {
      int c = lane + c4 * 64;
      float4 a = rrow[c], q = crow[c];
      float4 t = make_float4(q.x - a.x, q.y - a.y, q.z - a.z, q.w - a.w);
      float4 qst = make_float4(a.x + t.x, a.y + t.y, a.z + t.z, a.w + t.w);
      float4 rn = make_float4(a.x - qst.x, a.y - qst.y, a.z - qst.z, a.w - qst.w);
      orow[c] = rn;
      ssq_t += t.x * t.x + t.y * t.y + t.z * t.z + t.w * t.w;
      ssq_r += rn.x * rn.x + rn.y * rn.y + rn.z * rn.z + rn.w * rn.w;
    }
    float tot_t = wave_reduce_sum(ssq_t);
    float tot_r = wave_reduce_sum(ssq_r);
    if (lane == 0) {
      r2out[tok] = tot_r;
      lpart += tot_t;
    }
  }
  if (lane == 0) atomicAdd(lossCell, lpart);
}

// out_quant currently holds r_8; replace with x - r_8. Also emit final loss.
__global__ __launch_bounds__(256) void rvq_finalize_kernel(
    const float* __restrict__ x, float* __restrict__ out,
    const float* __restrict__ lossCell, float* __restrict__ loss_out) {
  size_t i = (size_t)blockIdx.x * 256 + threadIdx.x;
  const size_t n4 = (size_t)M_TOK * DIM / 4;  // 4,096,000
  if (i < n4) {
    const float4* x4 = (const float4*)x;
    float4* o4 = (float4*)out;
    float4 a = x4[i], r = o4[i];
    o4[i] = make_float4(a.x - r.x, a.y - r.y, a.z - r.z, a.w - r.w);
  }
  if (blockIdx.x == 0 && threadIdx.x == 0) {
    // mean over stages of 1.25*mean_elem(t^2): scale = 1.25 / (8 * 16384000)
    *loss_out = *lossCell * (1.25f / 131072000.f);
  }
}

extern "C" void kernel_launch(void* const* d_in, const int* in_sizes, int n_in,
                              void* d_out, int out_size, void* d_ws, size_t ws_size,
                              hipStream_t stream) {
  const float* x = (const float*)d_in[0];        // [16,2000,512]
  const float* cb = (const float*)d_in[1];       // [8,1024,512]
  float* out = (float*)d_out;                    // quantized region doubles as residual buffer
  float* idx_out = out + (size_t)M_TOK * DIM;    // [8][32000] indices as float
  float* loss_out = idx_out + (size_t)NQ * M_TOK;  // scalar
  // workspace: e2[8192] | r2[32000] | lossCell[1]
  float* e2 = (float*)d_ws;
  float* r2 = e2 + NQ * KCB;
  float* lossCell = r2 + M_TOK;

  {
    int rows = NQ * KCB + M_TOK;  // 40192
    rvq_init_kernel<<<(rows + 3) / 4, 256, 0, stream>>>(x, cb, e2, r2, lossCell);
  }
  float* resbuf = out;
  for (int s = 0; s < NQ; ++s) {
    rvq_stage_kernel<<<M_TOK / BM, 256, 0, stream>>>(
        s == 0 ? x : resbuf, cb + (size_t)s * KCB * DIM, e2 + s * KCB, r2,
        resbuf, r2, idx_out + (size_t)s * M_TOK, lossCell);
  }
  rvq_finalize_kernel<<<(M_TOK * DIM / 4 + 255) / 256, 256, 0, stream>>>(
      x, out, lossCell, loss_out);
}